// Round 6
// baseline (710.167 us; speedup 1.0000x reference)
//
#include <hip/hip_runtime.h>
#include <hip/hip_bf16.h>
#include <math.h>

#define BB   4
#define CC   32
#define HH   120
#define WW   160
#define NH_  8
#define HD   20
#define HDP  32            // head dim padded to 32 (zeros) for K=32 MFMA
#define NN   3840          // sequence length (C*H)
#define ROWS 3840
#define NBH  32            // B * NH
#define LOG2E 1.44269504088896f

typedef float f32x4 __attribute__((ext_vector_type(4)));
typedef short s16x8 __attribute__((ext_vector_type(8)));
typedef short s16x4 __attribute__((ext_vector_type(4)));

static __device__ __forceinline__ unsigned short f2bf(float x) {
    return __builtin_bit_cast(unsigned short, __float2bfloat16(x));
}
static __device__ __forceinline__ float bf2f(unsigned short u) {
    unsigned v = ((unsigned)u) << 16;
    return __builtin_bit_cast(float, v);
}
static __device__ __forceinline__ float exp2fast(float x) {
#if defined(__has_builtin) && __has_builtin(__builtin_amdgcn_exp2f)
    return __builtin_amdgcn_exp2f(x);
#else
    float r; asm("v_exp_f32 %0, %1" : "=v"(r) : "v"(x)); return r;
#endif
}

// exp2 four lanes -> packed bf16 B-frag via v_cvt_pk_bf16_f32 (RNE).
static __device__ __forceinline__ s16x4 exp4_pack(f32x4 e) {
    float a0 = exp2fast(e[0]), a1 = exp2fast(e[1]);
    float a2 = exp2fast(e[2]), a3 = exp2fast(e[3]);
    uint2 w;
    asm("v_cvt_pk_bf16_f32 %0, %1, %2" : "=v"(w.x) : "v"(a0), "v"(a1));
    asm("v_cvt_pk_bf16_f32 %0, %1, %2" : "=v"(w.y) : "v"(a2), "v"(a3));
    return __builtin_bit_cast(s16x4, w);
}

#if defined(__has_builtin)
#if __has_builtin(__builtin_amdgcn_mfma_f32_16x16x16bf16_1k)
#define HAVE_MFMA16_1K 1
#endif
#endif

static __device__ __forceinline__ f32x4 mfma16(s16x4 a, s16x4 b, f32x4 c) {
#ifdef HAVE_MFMA16_1K
    return __builtin_amdgcn_mfma_f32_16x16x16bf16_1k(a, b, c, 0, 0, 0);
#else
    asm volatile("v_mfma_f32_16x16x16_bf16 %0, %1, %2, %0" : "+v"(c) : "v"(a), "v"(b));
    return c;
#endif
}
static __device__ __forceinline__ f32x4 mfma32(s16x8 a, s16x8 b, f32x4 c) {
    return __builtin_amdgcn_mfma_f32_16x16x32_bf16(a, b, c, 0, 0, 0);
}

// ---------------- W prep: f32 -> bf16 [o][k]; Wq pre-scaled by log2(e) ----
__global__ __launch_bounds__(256)
void wprep_kernel(const float* __restrict__ Wq, const float* __restrict__ Wk,
                  const float* __restrict__ Wv,
                  unsigned short* __restrict__ wqb, unsigned short* __restrict__ wkb,
                  unsigned short* __restrict__ wvb)
{
    int i = blockIdx.x*256 + threadIdx.x;
    if (i < WW*WW) {
        wqb[i] = f2bf(Wq[i] * LOG2E);
        wkb[i] = f2bf(Wk[i]);
        wvb[i] = f2bf(Wv[i]);
    }
}

// ---------------- Projection via MFMA (no LDS) ---------------------------
__global__ __launch_bounds__(256)
void proj_mfma_kernel(const float* __restrict__ x,
                      const unsigned short* __restrict__ wqb,
                      const unsigned short* __restrict__ wkb,
                      const unsigned short* __restrict__ wvb,
                      const float* __restrict__ bq, const float* __restrict__ bk,
                      const float* __restrict__ bv,
                      unsigned short* __restrict__ qt, unsigned short* __restrict__ kt,
                      unsigned short* __restrict__ vb)
{
    const int tid  = threadIdx.x;
    const int wv   = tid >> 6;
    const int lane = tid & 63;
    const int g = lane >> 4, c = lane & 15;
    const int r0 = blockIdx.x*64 + wv*16;

    s16x8 A[5];
    const float* xrow = x + (size_t)(r0 + c)*WW;
    #pragma unroll
    for (int s = 0; s < 5; ++s) {
        float4 v0 = *(const float4*)(xrow + s*32 + g*8);
        float4 v1 = *(const float4*)(xrow + s*32 + g*8 + 4);
        s16x8 a;
        a[0]=(short)f2bf(v0.x); a[1]=(short)f2bf(v0.y);
        a[2]=(short)f2bf(v0.z); a[3]=(short)f2bf(v0.w);
        a[4]=(short)f2bf(v1.x); a[5]=(short)f2bf(v1.y);
        a[6]=(short)f2bf(v1.z); a[7]=(short)f2bf(v1.w);
        A[s] = a;
    }

    size_t baseqk[4], basev[4];
    #pragma unroll
    for (int rr = 0; rr < 4; ++rr) {
        int R  = r0 + g*4 + rr;
        int b  = R / ROWS;
        int r  = R % ROWS;
        int nh = r / 480;
        int rm = r % 480;
        int d  = rm / 24;
        int n1 = rm % 24;
        int bh = b*NH_ + nh;
        baseqk[rr] = ((size_t)bh*NN + n1*160)*HDP + d;
        basev[rr]  = ((size_t)bh*HD + d)*NN + n1*160;
    }

    const f32x4 zero4 = {0.f, 0.f, 0.f, 0.f};
    for (int nt = 0; nt < 10; ++nt) {
        const size_t wbase = (size_t)(nt*16 + c)*WW;
        f32x4 aq = zero4, ak = zero4, av = zero4;
        #pragma unroll
        for (int s = 0; s < 5; ++s) {
            s16x8 Bq = *(const s16x8*)(wqb + wbase + s*32 + g*8);
            aq = mfma32(A[s], Bq, aq);
            s16x8 Bk = *(const s16x8*)(wkb + wbase + s*32 + g*8);
            ak = mfma32(A[s], Bk, ak);
            s16x8 Bv = *(const s16x8*)(wvb + wbase + s*32 + g*8);
            av = mfma32(A[s], Bv, av);
        }
        const int o = nt*16 + c;
        const float bqv = bq[o]*LOG2E, bkv = bk[o], bvv = bv[o];
        #pragma unroll
        for (int rr = 0; rr < 4; ++rr) {
            qt[baseqk[rr] + (size_t)o*HDP] = f2bf(aq[rr] + bqv);
            kt[baseqk[rr] + (size_t)o*HDP] = f2bf(ak[rr] + bkv);
            vb[basev[rr] + o]              = f2bf(av[rr] + bvv);
        }
    }
}

// ---------------- Pass 1: zinv[m] = 1 / sum_n exp2(E[m,n]) ---------------
// Block = 64 m-rows; wave wv owns 16 of them (qa fixed in regs) and ALL
// waves sweep the full n-range together -> in-loop kb loads are
// wave-identical (L1-shared). No LDS.
__global__ __launch_bounds__(256)
void zinv_kernel(const unsigned short* __restrict__ qt,
                 const unsigned short* __restrict__ kt,
                 float* __restrict__ zinv)
{
    const int blk  = blockIdx.x;
    const int bh   = blk / (NN/64);
    const int mrow = (blk % (NN/64)) * 64 + (threadIdx.x >> 6) * 16;
    const int lane = threadIdx.x & 63;
    const int g = lane >> 4, c = lane & 15;

    const unsigned short* qb  = qt + (size_t)bh*NN*HDP;
    const unsigned short* kbp = kt + (size_t)bh*NN*HDP;

    const s16x8 qa = *(const s16x8*)(qb + (size_t)(mrow + c)*HDP + g*8);

    const f32x4 zero4 = {0.f, 0.f, 0.f, 0.f};
    f32x4 z = zero4;

    for (int n = 0; n < NN; n += 32) {
        if ((n & 255) == 0) __syncthreads();   // keep waves lockstep for L1 reuse
        s16x8 kb0 = *(const s16x8*)(kbp + (size_t)(n +      c)*HDP + g*8);
        s16x8 kb1 = *(const s16x8*)(kbp + (size_t)(n + 16 + c)*HDP + g*8);
        f32x4 e0 = mfma32(qa, kb0, zero4);
        f32x4 e1 = mfma32(qa, kb1, zero4);
        #pragma unroll
        for (int rr = 0; rr < 4; ++rr)
            z[rr] += exp2fast(e0[rr]) + exp2fast(e1[rr]);
    }
    #pragma unroll
    for (int rr = 0; rr < 4; ++rr) {
        float v = z[rr];
        v += __shfl_xor(v, 1);
        v += __shfl_xor(v, 2);
        v += __shfl_xor(v, 4);
        v += __shfl_xor(v, 8);
        if (c == 0)
            zinv[(size_t)bh*NN + mrow + g*4 + rr] = 1.0f / v;
    }
}

// ---------------- vzb[bh][dp][m] = bf16(v[dp][m] * zinv[m]), pad rows 0 --
__global__ __launch_bounds__(256)
void vz_kernel(const unsigned short* __restrict__ vb,
               const float* __restrict__ zinv,
               unsigned short* __restrict__ vzb)
{
    size_t idx = (size_t)blockIdx.x*256 + threadIdx.x;   // over NBH*HDP*NN
    int m  = (int)(idx % NN);
    int t  = (int)(idx / NN);
    int dp = t % HDP;
    int bh = t / HDP;
    float val = 0.f;
    if (dp < HD)
        val = bf2f(vb[((size_t)bh*HD + dp)*NN + m]) * zinv[(size_t)bh*NN + m];
    vzb[idx] = f2bf(val);
}

// ---------------- Pass 2: out = Vz * exp2(Q^T K) ------------------------
// Block = 64 n-cols; wave wv owns 16 of them (kb fixed in regs); ALL waves
// sweep the full m-range together -> qa/va in-loop loads are wave-identical
// (L1-shared). Each wave writes its own output cols: no LDS reduce.
__global__ __launch_bounds__(256)
void attn_out_kernel(const unsigned short* __restrict__ qt,
                     const unsigned short* __restrict__ kt,
                     const unsigned short* __restrict__ vzb,
                     float* __restrict__ y)
{
    const int blk  = blockIdx.x;
    const int bh   = blk / (NN/64);
    const int ncol = (blk % (NN/64)) * 64 + (threadIdx.x >> 6) * 16;
    const int lane = threadIdx.x & 63;
    const int g = lane >> 4, c = lane & 15;
    const int b = bh >> 3, nh = bh & 7;

    const f32x4 zero4 = {0.f, 0.f, 0.f, 0.f};
    const unsigned short* qb  = qt  + (size_t)bh*NN*HDP;
    const unsigned short* kbp = kt  + (size_t)bh*NN*HDP;
    const unsigned short* vp  = vzb + (size_t)bh*HDP*NN;

    const s16x8 kb = *(const s16x8*)(kbp + (size_t)(ncol + c)*HDP + g*8);

    f32x4 acc[2] = {zero4, zero4};

    for (int m0 = 0; m0 < NN; m0 += 32) {
        if ((m0 & 255) == 0) __syncthreads();   // keep waves lockstep for L1 reuse
        s16x8 qa0 = *(const s16x8*)(qb + (size_t)(m0 +      c)*HDP + g*8);
        s16x8 qa1 = *(const s16x8*)(qb + (size_t)(m0 + 16 + c)*HDP + g*8);
        s16x4 va[2][2];
        #pragma unroll
        for (int ds = 0; ds < 2; ++ds)
            #pragma unroll
            for (int ms = 0; ms < 2; ++ms)
                va[ds][ms] = *(const s16x4*)(vp + (size_t)(ds*16 + c)*NN
                                                + m0 + ms*16 + g*4);
        f32x4 e0 = mfma32(qa0, kb, zero4);
        f32x4 e1 = mfma32(qa1, kb, zero4);
        s16x4 p0 = exp4_pack(e0);
        s16x4 p1 = exp4_pack(e1);
        acc[0] = mfma16(va[0][0], p0, acc[0]);
        acc[0] = mfma16(va[0][1], p1, acc[0]);
        acc[1] = mfma16(va[1][0], p0, acc[1]);
        acc[1] = mfma16(va[1][1], p1, acc[1]);
    }

    float* yb = y + (size_t)b * CC * HH * WW;
    #pragma unroll
    for (int ds = 0; ds < 2; ++ds) {
        #pragma unroll
        for (int rr = 0; rr < 4; ++rr) {
            int dd = ds*16 + g*4 + rr;
            if (dd < HD)
                yb[((size_t)(dd*NH_ + nh))*NN + ncol + c] = acc[ds][rr];
        }
    }
}

extern "C" void kernel_launch(void* const* d_in, const int* in_sizes, int n_in,
                              void* d_out, int out_size, void* d_ws, size_t ws_size,
                              hipStream_t stream)
{
    const float* x  = (const float*)d_in[0];
    const float* Wq = (const float*)d_in[1];
    const float* bq = (const float*)d_in[2];
    const float* Wk = (const float*)d_in[3];
    const float* bk = (const float*)d_in[4];
    const float* Wv = (const float*)d_in[5];
    const float* bv = (const float*)d_in[6];
    float* y = (float*)d_out;

    const size_t QT_E = (size_t)NBH * NN * HDP;      // 3,932,160 bf16
    unsigned short* qt  = (unsigned short*)d_ws;
    unsigned short* kt  = qt + QT_E;
    unsigned short* vb  = kt + QT_E;
    unsigned short* vzb = vb + (size_t)NBH * HD * NN;
    float*          zinv = (float*)(vzb + QT_E);
    unsigned short* wqb = (unsigned short*)(zinv + (size_t)NBH*NN);
    unsigned short* wkb = wqb + WW*WW;
    unsigned short* wvb = wkb + WW*WW;               // total ~29.2 MB

    hipMemsetAsync(qt, 0, 2 * QT_E * sizeof(unsigned short), stream);

    wprep_kernel<<<dim3((WW*WW + 255)/256), dim3(256), 0, stream>>>(
        Wq, Wk, Wv, wqb, wkb, wvb);
    proj_mfma_kernel<<<dim3(BB*ROWS/64), dim3(256), 0, stream>>>(
        x, wqb, wkb, wvb, bq, bk, bv, qt, kt, vb);
    zinv_kernel<<<dim3(NBH*(NN/64)), dim3(256), 0, stream>>>(qt, kt, zinv);
    vz_kernel<<<dim3((NBH*HDP*NN)/256), dim3(256), 0, stream>>>(vb, zinv, vzb);
    attn_out_kernel<<<dim3(NBH*(NN/64)), dim3(256), 0, stream>>>(qt, kt, vzb, y);
}

// Round 9
// 263.382 us; speedup vs baseline: 2.6963x; 2.6963x over previous
//
#include <hip/hip_runtime.h>
#include <hip/hip_bf16.h>
#include <math.h>

#define BB   4
#define CC   32
#define HH   120
#define WW   160
#define NH_  8
#define HD   20
#define HDP  32            // head dim padded to 32 (zeros) for K=32 MFMA
#define NN   3840          // sequence length (C*H)
#define ROWS 3840
#define NBH  32            // B * NH
#define LOG2E 1.44269504088896f

typedef float f32x4 __attribute__((ext_vector_type(4)));
typedef short s16x8 __attribute__((ext_vector_type(8)));
typedef short s16x4 __attribute__((ext_vector_type(4)));

static __device__ __forceinline__ unsigned short f2bf(float x) {
    return __builtin_bit_cast(unsigned short, __float2bfloat16(x));
}
static __device__ __forceinline__ float bf2f(unsigned short u) {
    unsigned v = ((unsigned)u) << 16;
    return __builtin_bit_cast(float, v);
}
static __device__ __forceinline__ float exp2fast(float x) {
#if defined(__has_builtin) && __has_builtin(__builtin_amdgcn_exp2f)
    return __builtin_amdgcn_exp2f(x);
#else
    float r; asm("v_exp_f32 %0, %1" : "=v"(r) : "v"(x)); return r;
#endif
}

// exp2 four lanes then pack to bf16 (round-half-up) as an s16x4 B-frag.
// BUILTIN-ONLY pack (no inline asm): validated passing in the Round-5 bench
// (absmax 0.015625) in this exact dataflow position. The cvt_pk inline-asm
// variant corrupts in the unrolled S160 loop (R7/R8 failures) — do not use.
static __device__ __forceinline__ s16x4 exp4_pack(f32x4 e) {
    unsigned u0 = __builtin_bit_cast(unsigned, exp2fast(e[0])) + 0x8000u;
    unsigned u1 = __builtin_bit_cast(unsigned, exp2fast(e[1])) + 0x8000u;
    unsigned u2 = __builtin_bit_cast(unsigned, exp2fast(e[2])) + 0x8000u;
    unsigned u3 = __builtin_bit_cast(unsigned, exp2fast(e[3])) + 0x8000u;
    uint2 w;
#if defined(__has_builtin) && __has_builtin(__builtin_amdgcn_perm)
    w.x = __builtin_amdgcn_perm(u1, u0, 0x07060302u);
    w.y = __builtin_amdgcn_perm(u3, u2, 0x07060302u);
#else
    w.x = (u0 >> 16) | (u1 & 0xffff0000u);
    w.y = (u2 >> 16) | (u3 & 0xffff0000u);
#endif
    return __builtin_bit_cast(s16x4, w);
}

#if defined(__has_builtin)
#if __has_builtin(__builtin_amdgcn_mfma_f32_16x16x16bf16_1k)
#define HAVE_MFMA16_1K 1
#endif
#endif

static __device__ __forceinline__ f32x4 mfma16(s16x4 a, s16x4 b, f32x4 c) {
#ifdef HAVE_MFMA16_1K
    return __builtin_amdgcn_mfma_f32_16x16x16bf16_1k(a, b, c, 0, 0, 0);
#else
    asm volatile("v_mfma_f32_16x16x16_bf16 %0, %1, %2, %0" : "+v"(c) : "v"(a), "v"(b));
    return c;
#endif
}
static __device__ __forceinline__ f32x4 mfma32(s16x8 a, s16x8 b, f32x4 c) {
    return __builtin_amdgcn_mfma_f32_16x16x32_bf16(a, b, c, 0, 0, 0);
}

// ---------------- W prep: f32 -> bf16 [o][k]; Wq pre-scaled by log2(e) ----
__global__ __launch_bounds__(256)
void wprep_kernel(const float* __restrict__ Wq, const float* __restrict__ Wk,
                  const float* __restrict__ Wv,
                  unsigned short* __restrict__ wqb, unsigned short* __restrict__ wkb,
                  unsigned short* __restrict__ wvb)
{
    int i = blockIdx.x*256 + threadIdx.x;
    if (i < WW*WW) {
        wqb[i] = f2bf(Wq[i] * LOG2E);
        wkb[i] = f2bf(Wk[i]);
        wvb[i] = f2bf(Wv[i]);
    }
}

// ---------------- Projection via MFMA (no LDS) ---------------------------
__global__ __launch_bounds__(256)
void proj_mfma_kernel(const float* __restrict__ x,
                      const unsigned short* __restrict__ wqb,
                      const unsigned short* __restrict__ wkb,
                      const unsigned short* __restrict__ wvb,
                      const float* __restrict__ bq, const float* __restrict__ bk,
                      const float* __restrict__ bv,
                      unsigned short* __restrict__ qt, unsigned short* __restrict__ kt,
                      unsigned short* __restrict__ vb)
{
    const int tid  = threadIdx.x;
    const int wv   = tid >> 6;
    const int lane = tid & 63;
    const int g = lane >> 4, c = lane & 15;
    const int r0 = blockIdx.x*64 + wv*16;

    s16x8 A[5];
    const float* xrow = x + (size_t)(r0 + c)*WW;
    #pragma unroll
    for (int s = 0; s < 5; ++s) {
        float4 v0 = *(const float4*)(xrow + s*32 + g*8);
        float4 v1 = *(const float4*)(xrow + s*32 + g*8 + 4);
        s16x8 a;
        a[0]=(short)f2bf(v0.x); a[1]=(short)f2bf(v0.y);
        a[2]=(short)f2bf(v0.z); a[3]=(short)f2bf(v0.w);
        a[4]=(short)f2bf(v1.x); a[5]=(short)f2bf(v1.y);
        a[6]=(short)f2bf(v1.z); a[7]=(short)f2bf(v1.w);
        A[s] = a;
    }

    size_t baseqk[4], basev[4];
    #pragma unroll
    for (int rr = 0; rr < 4; ++rr) {
        int R  = r0 + g*4 + rr;
        int b  = R / ROWS;
        int r  = R % ROWS;
        int nh = r / 480;
        int rm = r % 480;
        int d  = rm / 24;
        int n1 = rm % 24;
        int bh = b*NH_ + nh;
        baseqk[rr] = ((size_t)bh*NN + n1*160)*HDP + d;
        basev[rr]  = ((size_t)bh*HD + d)*NN + n1*160;
    }

    const f32x4 zero4 = {0.f, 0.f, 0.f, 0.f};
    for (int nt = 0; nt < 10; ++nt) {
        const size_t wbase = (size_t)(nt*16 + c)*WW;
        f32x4 aq = zero4, ak = zero4, av = zero4;
        #pragma unroll
        for (int s = 0; s < 5; ++s) {
            s16x8 Bq = *(const s16x8*)(wqb + wbase + s*32 + g*8);
            aq = mfma32(A[s], Bq, aq);
            s16x8 Bk = *(const s16x8*)(wkb + wbase + s*32 + g*8);
            ak = mfma32(A[s], Bk, ak);
            s16x8 Bv = *(const s16x8*)(wvb + wbase + s*32 + g*8);
            av = mfma32(A[s], Bv, av);
        }
        const int o = nt*16 + c;
        const float bqv = bq[o]*LOG2E, bkv = bk[o], bvv = bv[o];
        #pragma unroll
        for (int rr = 0; rr < 4; ++rr) {
            qt[baseqk[rr] + (size_t)o*HDP] = f2bf(aq[rr] + bqv);
            kt[baseqk[rr] + (size_t)o*HDP] = f2bf(ak[rr] + bkv);
            vb[basev[rr] + o]              = f2bf(av[rr] + bvv);
        }
    }
}

// ---------------- Pass 1: zinv[m] = 1 / sum_n exp2(E[m,n]) ---------------
// 1920 blocks: block owns 64 m-rows; 4 waves split the n-range.
__global__ __launch_bounds__(256)
void zinv_kernel(const unsigned short* __restrict__ qt,
                 const unsigned short* __restrict__ kt,
                 float* __restrict__ zinv)
{
    __shared__ float zred[4][64];
    const int blk  = blockIdx.x;
    const int bh   = blk / (NN/64);
    const int m0   = (blk % (NN/64)) * 64;
    const int tid  = threadIdx.x;
    const int wv   = tid >> 6;
    const int lane = tid & 63;
    const int g = lane >> 4, c = lane & 15;

    s16x8 qa[4];
    #pragma unroll
    for (int ms = 0; ms < 4; ++ms)
        qa[ms] = *(const s16x8*)(qt + ((size_t)bh*NN + m0 + ms*16 + c)*HDP + g*8);

    const f32x4 zero4 = {0.f, 0.f, 0.f, 0.f};
    f32x4 z[4];
    #pragma unroll
    for (int ms = 0; ms < 4; ++ms) z[ms] = zero4;

    const int nbeg = wv * (NN/4);
    for (int n = nbeg; n < nbeg + NN/4; n += 32) {
        s16x8 kb0 = *(const s16x8*)(kt + ((size_t)bh*NN + n +      c)*HDP + g*8);
        s16x8 kb1 = *(const s16x8*)(kt + ((size_t)bh*NN + n + 16 + c)*HDP + g*8);
        #pragma unroll
        for (int ms = 0; ms < 4; ++ms) {
            f32x4 e0 = mfma32(qa[ms], kb0, zero4);
            f32x4 e1 = mfma32(qa[ms], kb1, zero4);
            #pragma unroll
            for (int rr = 0; rr < 4; ++rr)
                z[ms][rr] += exp2fast(e0[rr]) + exp2fast(e1[rr]);
        }
    }
    #pragma unroll
    for (int ms = 0; ms < 4; ++ms) {
        #pragma unroll
        for (int rr = 0; rr < 4; ++rr) {
            float v = z[ms][rr];
            v += __shfl_xor(v, 1);
            v += __shfl_xor(v, 2);
            v += __shfl_xor(v, 4);
            v += __shfl_xor(v, 8);
            if (c == 0) zred[wv][ms*16 + g*4 + rr] = v;
        }
    }
    __syncthreads();
    if (tid < 64) {
        float s = zred[0][tid] + zred[1][tid] + zred[2][tid] + zred[3][tid];
        zinv[(size_t)bh*NN + m0 + tid] = 1.0f / s;
    }
}

// ---------------- vzb[bh][dp][m] = bf16(v[dp][m] * zinv[m]), pad rows 0 --
__global__ __launch_bounds__(256)
void vz_kernel(const unsigned short* __restrict__ vb,
               const float* __restrict__ zinv,
               unsigned short* __restrict__ vzb)
{
    size_t idx = (size_t)blockIdx.x*256 + threadIdx.x;   // over NBH*HDP*NN
    int m  = (int)(idx % NN);
    int t  = (int)(idx / NN);
    int dp = t % HDP;
    int bh = t / HDP;
    float val = 0.f;
    if (dp < HD)
        val = bf2f(vb[((size_t)bh*HD + dp)*NN + m]) * zinv[(size_t)bh*NN + m];
    vzb[idx] = f2bf(val);
}

// ---------------- Pass 2: out = Vz * exp2(Q^T K) ------------------------
// S160 structure (Round-4 bench: attn=160us). ONLY delta: perm-pack.
// 1920 blocks: block owns 64 n-cols, kb[4] in regs; 4 waves each accumulate
// a private m-quarter (8 indep E-chains of ILP); LDS reduce; wave 0 writes.
__global__ __launch_bounds__(256)
void attn_out_kernel(const unsigned short* __restrict__ qt,
                     const unsigned short* __restrict__ kt,
                     const unsigned short* __restrict__ vzb,
                     float* __restrict__ y)
{
    __shared__ float red[3][32][64];   // 24 KB: waves 1..3 partials
    const int blk  = blockIdx.x;
    const int bh   = blk / (NN/64);
    const int n0   = (blk % (NN/64)) * 64;
    const int tid  = threadIdx.x;
    const int wv   = tid >> 6;
    const int lane = tid & 63;
    const int g = lane >> 4, c = lane & 15;
    const int b = bh >> 3, nh = bh & 7;

    const f32x4 zero4 = {0.f, 0.f, 0.f, 0.f};
    const unsigned short* qb  = qt  + (size_t)bh*NN*HDP;
    const unsigned short* kbp = kt  + (size_t)bh*NN*HDP;
    const unsigned short* vp  = vzb + (size_t)bh*HDP*NN;

    s16x8 kb[4];
    #pragma unroll
    for (int ns = 0; ns < 4; ++ns)
        kb[ns] = *(const s16x8*)(kbp + ((size_t)(n0 + ns*16 + c))*HDP + g*8);

    f32x4 acc[2][4];
    #pragma unroll
    for (int ds = 0; ds < 2; ++ds)
        #pragma unroll
        for (int ns = 0; ns < 4; ++ns) acc[ds][ns] = zero4;

    const int mbeg = wv * (NN/4);
    for (int m0 = mbeg; m0 < mbeg + NN/4; m0 += 32) {
        s16x8 qa0 = *(const s16x8*)(qb + ((size_t)(m0 +      c))*HDP + g*8);
        s16x8 qa1 = *(const s16x8*)(qb + ((size_t)(m0 + 16 + c))*HDP + g*8);
        s16x4 va[2][2];
        #pragma unroll
        for (int ds = 0; ds < 2; ++ds)
            #pragma unroll
            for (int ms = 0; ms < 2; ++ms)
                va[ds][ms] = *(const s16x4*)(vp + ((size_t)(ds*16 + c))*NN
                                                + m0 + ms*16 + g*4);
        #pragma unroll
        for (int ns = 0; ns < 4; ++ns) {
            f32x4 e0 = mfma32(qa0, kb[ns], zero4);
            f32x4 e1 = mfma32(qa1, kb[ns], zero4);
            s16x4 p0 = exp4_pack(e0);
            s16x4 p1 = exp4_pack(e1);
            acc[0][ns] = mfma16(va[0][0], p0, acc[0][ns]);
            acc[0][ns] = mfma16(va[0][1], p1, acc[0][ns]);
            acc[1][ns] = mfma16(va[1][0], p0, acc[1][ns]);
            acc[1][ns] = mfma16(va[1][1], p1, acc[1][ns]);
        }
    }

    float* af = (float*)acc;   // 32 contiguous f32
    if (wv > 0) {
        #pragma unroll
        for (int j = 0; j < 32; ++j) red[wv-1][j][lane] = af[j];
    }
    __syncthreads();
    if (wv == 0) {
        #pragma unroll
        for (int j = 0; j < 32; ++j)
            af[j] += red[0][j][lane] + red[1][j][lane] + red[2][j][lane];
        float* yb = y + (size_t)b * CC * HH * WW;
        #pragma unroll
        for (int ds = 0; ds < 2; ++ds) {
            #pragma unroll
            for (int ns = 0; ns < 4; ++ns) {
                #pragma unroll
                for (int rr = 0; rr < 4; ++rr) {
                    int dd = ds*16 + g*4 + rr;
                    if (dd < HD)
                        yb[((size_t)(dd*NH_ + nh))*NN + n0 + ns*16 + c] = acc[ds][ns][rr];
                }
            }
        }
    }
}

extern "C" void kernel_launch(void* const* d_in, const int* in_sizes, int n_in,
                              void* d_out, int out_size, void* d_ws, size_t ws_size,
                              hipStream_t stream)
{
    const float* x  = (const float*)d_in[0];
    const float* Wq = (const float*)d_in[1];
    const float* bq = (const float*)d_in[2];
    const float* Wk = (const float*)d_in[3];
    const float* bk = (const float*)d_in[4];
    const float* Wv = (const float*)d_in[5];
    const float* bv = (const float*)d_in[6];
    float* y = (float*)d_out;

    const size_t QT_E = (size_t)NBH * NN * HDP;      // 3,932,160 bf16
    unsigned short* qt  = (unsigned short*)d_ws;
    unsigned short* kt  = qt + QT_E;
    unsigned short* vb  = kt + QT_E;
    unsigned short* vzb = vb + (size_t)NBH * HD * NN;
    float*          zinv = (float*)(vzb + QT_E);
    unsigned short* wqb = (unsigned short*)(zinv + (size_t)NBH*NN);
    unsigned short* wkb = wqb + WW*WW;
    unsigned short* wvb = wkb + WW*WW;               // total ~29.2 MB

    hipMemsetAsync(qt, 0, 2 * QT_E * sizeof(unsigned short), stream);

    wprep_kernel<<<dim3((WW*WW + 255)/256), dim3(256), 0, stream>>>(
        Wq, Wk, Wv, wqb, wkb, wvb);
    proj_mfma_kernel<<<dim3(BB*ROWS/64), dim3(256), 0, stream>>>(
        x, wqb, wkb, wvb, bq, bk, bv, qt, kt, vb);
    zinv_kernel<<<dim3(NBH*(NN/64)), dim3(256), 0, stream>>>(qt, kt, zinv);
    vz_kernel<<<dim3((NBH*HDP*NN)/256), dim3(256), 0, stream>>>(vb, zinv, vzb);
    attn_out_kernel<<<dim3(NBH*(NN/64)), dim3(256), 0, stream>>>(qt, kt, vzb, y);
}

// Round 10
// 249.582 us; speedup vs baseline: 2.8454x; 1.0553x over previous
//
#include <hip/hip_runtime.h>
#include <hip/hip_bf16.h>
#include <math.h>

#define BB   4
#define CC   32
#define HH   120
#define WW   160
#define NH_  8
#define HD   20
#define HDP  32            // head dim padded to 32 (zeros) for K=32 MFMA
#define NN   3840          // sequence length (C*H)
#define ROWS 3840
#define NBH  32            // B * NH
#define LOG2E 1.44269504088896f

typedef float f32x4 __attribute__((ext_vector_type(4)));
typedef short s16x8 __attribute__((ext_vector_type(8)));
typedef short s16x4 __attribute__((ext_vector_type(4)));

static __device__ __forceinline__ unsigned short f2bf(float x) {
    return __builtin_bit_cast(unsigned short, __float2bfloat16(x));
}
static __device__ __forceinline__ float bf2f(unsigned short u) {
    unsigned v = ((unsigned)u) << 16;
    return __builtin_bit_cast(float, v);
}
static __device__ __forceinline__ float exp2fast(float x) {
#if defined(__has_builtin) && __has_builtin(__builtin_amdgcn_exp2f)
    return __builtin_amdgcn_exp2f(x);
#else
    float r; asm("v_exp_f32 %0, %1" : "=v"(r) : "v"(x)); return r;
#endif
}

// exp2 four lanes then pack to bf16 (round-half-up) as an s16x4 B-frag.
// BUILTIN-ONLY pack — validated passing in R5/R9 benches. Do NOT use the
// cvt_pk inline-asm variant (R7/R8 corruption in unrolled loops).
static __device__ __forceinline__ s16x4 exp4_pack(f32x4 e) {
    unsigned u0 = __builtin_bit_cast(unsigned, exp2fast(e[0])) + 0x8000u;
    unsigned u1 = __builtin_bit_cast(unsigned, exp2fast(e[1])) + 0x8000u;
    unsigned u2 = __builtin_bit_cast(unsigned, exp2fast(e[2])) + 0x8000u;
    unsigned u3 = __builtin_bit_cast(unsigned, exp2fast(e[3])) + 0x8000u;
    uint2 w;
#if defined(__has_builtin) && __has_builtin(__builtin_amdgcn_perm)
    w.x = __builtin_amdgcn_perm(u1, u0, 0x07060302u);
    w.y = __builtin_amdgcn_perm(u3, u2, 0x07060302u);
#else
    w.x = (u0 >> 16) | (u1 & 0xffff0000u);
    w.y = (u2 >> 16) | (u3 & 0xffff0000u);
#endif
    return __builtin_bit_cast(s16x4, w);
}

#if defined(__has_builtin)
#if __has_builtin(__builtin_amdgcn_mfma_f32_16x16x16bf16_1k)
#define HAVE_MFMA16_1K 1
#endif
#endif

static __device__ __forceinline__ f32x4 mfma16(s16x4 a, s16x4 b, f32x4 c) {
#ifdef HAVE_MFMA16_1K
    return __builtin_amdgcn_mfma_f32_16x16x16bf16_1k(a, b, c, 0, 0, 0);
#else
    asm volatile("v_mfma_f32_16x16x16_bf16 %0, %1, %2, %0" : "+v"(c) : "v"(a), "v"(b));
    return c;
#endif
}
static __device__ __forceinline__ f32x4 mfma32(s16x8 a, s16x8 b, f32x4 c) {
    return __builtin_amdgcn_mfma_f32_16x16x32_bf16(a, b, c, 0, 0, 0);
}

// ---------------- W prep: f32 -> bf16 [o][k]; Wq pre-scaled by log2(e) ----
__global__ __launch_bounds__(256)
void wprep_kernel(const float* __restrict__ Wq, const float* __restrict__ Wk,
                  const float* __restrict__ Wv,
                  unsigned short* __restrict__ wqb, unsigned short* __restrict__ wkb,
                  unsigned short* __restrict__ wvb)
{
    int i = blockIdx.x*256 + threadIdx.x;
    if (i < WW*WW) {
        wqb[i] = f2bf(Wq[i] * LOG2E);
        wkb[i] = f2bf(Wk[i]);
        wvb[i] = f2bf(Wv[i]);
    }
}

// ---------------- Projection via MFMA (no LDS) ---------------------------
__global__ __launch_bounds__(256)
void proj_mfma_kernel(const float* __restrict__ x,
                      const unsigned short* __restrict__ wqb,
                      const unsigned short* __restrict__ wkb,
                      const unsigned short* __restrict__ wvb,
                      const float* __restrict__ bq, const float* __restrict__ bk,
                      const float* __restrict__ bv,
                      unsigned short* __restrict__ qt, unsigned short* __restrict__ kt,
                      unsigned short* __restrict__ vb)
{
    const int tid  = threadIdx.x;
    const int wv   = tid >> 6;
    const int lane = tid & 63;
    const int g = lane >> 4, c = lane & 15;
    const int r0 = blockIdx.x*64 + wv*16;

    s16x8 A[5];
    const float* xrow = x + (size_t)(r0 + c)*WW;
    #pragma unroll
    for (int s = 0; s < 5; ++s) {
        float4 v0 = *(const float4*)(xrow + s*32 + g*8);
        float4 v1 = *(const float4*)(xrow + s*32 + g*8 + 4);
        s16x8 a;
        a[0]=(short)f2bf(v0.x); a[1]=(short)f2bf(v0.y);
        a[2]=(short)f2bf(v0.z); a[3]=(short)f2bf(v0.w);
        a[4]=(short)f2bf(v1.x); a[5]=(short)f2bf(v1.y);
        a[6]=(short)f2bf(v1.z); a[7]=(short)f2bf(v1.w);
        A[s] = a;
    }

    size_t baseqk[4], basev[4];
    #pragma unroll
    for (int rr = 0; rr < 4; ++rr) {
        int R  = r0 + g*4 + rr;
        int b  = R / ROWS;
        int r  = R % ROWS;
        int nh = r / 480;
        int rm = r % 480;
        int d  = rm / 24;
        int n1 = rm % 24;
        int bh = b*NH_ + nh;
        baseqk[rr] = ((size_t)bh*NN + n1*160)*HDP + d;
        basev[rr]  = ((size_t)bh*HD + d)*NN + n1*160;
    }

    const f32x4 zero4 = {0.f, 0.f, 0.f, 0.f};
    for (int nt = 0; nt < 10; ++nt) {
        const size_t wbase = (size_t)(nt*16 + c)*WW;
        f32x4 aq = zero4, ak = zero4, av = zero4;
        #pragma unroll
        for (int s = 0; s < 5; ++s) {
            s16x8 Bq = *(const s16x8*)(wqb + wbase + s*32 + g*8);
            aq = mfma32(A[s], Bq, aq);
            s16x8 Bk = *(const s16x8*)(wkb + wbase + s*32 + g*8);
            ak = mfma32(A[s], Bk, ak);
            s16x8 Bv = *(const s16x8*)(wvb + wbase + s*32 + g*8);
            av = mfma32(A[s], Bv, av);
        }
        const int o = nt*16 + c;
        const float bqv = bq[o]*LOG2E, bkv = bk[o], bvv = bv[o];
        #pragma unroll
        for (int rr = 0; rr < 4; ++rr) {
            qt[baseqk[rr] + (size_t)o*HDP] = f2bf(aq[rr] + bqv);
            kt[baseqk[rr] + (size_t)o*HDP] = f2bf(ak[rr] + bkv);
            vb[basev[rr] + o]              = f2bf(av[rr] + bvv);
        }
    }
}

// ---------------- Pass 1: zinv[m] = 1 / sum_n exp2(E[m,n]) ---------------
// 1920 blocks: block owns 64 m-rows; 4 waves split the n-range.
// R10: __launch_bounds__(256,4) (128 VGPR) + 1-deep K-frag prefetch pipeline.
__global__ __launch_bounds__(256, 4)
void zinv_kernel(const unsigned short* __restrict__ qt,
                 const unsigned short* __restrict__ kt,
                 float* __restrict__ zinv)
{
    __shared__ float zred[4][64];
    const int blk  = blockIdx.x;
    const int bh   = blk / (NN/64);
    const int m0   = (blk % (NN/64)) * 64;
    const int tid  = threadIdx.x;
    const int wv   = tid >> 6;
    const int lane = tid & 63;
    const int g = lane >> 4, c = lane & 15;

    s16x8 qa[4];
    #pragma unroll
    for (int ms = 0; ms < 4; ++ms)
        qa[ms] = *(const s16x8*)(qt + ((size_t)bh*NN + m0 + ms*16 + c)*HDP + g*8);

    const f32x4 zero4 = {0.f, 0.f, 0.f, 0.f};
    f32x4 z[4];
    #pragma unroll
    for (int ms = 0; ms < 4; ++ms) z[ms] = zero4;

    const unsigned short* kbase = kt + (size_t)bh*NN*HDP;
    const int nbeg = wv * (NN/4);
    const int nend = nbeg + NN/4;

    // prologue: load first K-frags
    s16x8 kb0 = *(const s16x8*)(kbase + (size_t)(nbeg +      c)*HDP + g*8);
    s16x8 kb1 = *(const s16x8*)(kbase + (size_t)(nbeg + 16 + c)*HDP + g*8);

    for (int n = nbeg; n < nend - 32; n += 32) {
        // issue next step's loads before computing current step
        s16x8 nk0 = *(const s16x8*)(kbase + (size_t)(n + 32 +      c)*HDP + g*8);
        s16x8 nk1 = *(const s16x8*)(kbase + (size_t)(n + 48 +      c)*HDP + g*8);
        #pragma unroll
        for (int ms = 0; ms < 4; ++ms) {
            f32x4 e0 = mfma32(qa[ms], kb0, zero4);
            f32x4 e1 = mfma32(qa[ms], kb1, zero4);
            #pragma unroll
            for (int rr = 0; rr < 4; ++rr)
                z[ms][rr] += exp2fast(e0[rr]) + exp2fast(e1[rr]);
        }
        kb0 = nk0; kb1 = nk1;
    }
    // epilogue: last step
    #pragma unroll
    for (int ms = 0; ms < 4; ++ms) {
        f32x4 e0 = mfma32(qa[ms], kb0, zero4);
        f32x4 e1 = mfma32(qa[ms], kb1, zero4);
        #pragma unroll
        for (int rr = 0; rr < 4; ++rr)
            z[ms][rr] += exp2fast(e0[rr]) + exp2fast(e1[rr]);
    }

    #pragma unroll
    for (int ms = 0; ms < 4; ++ms) {
        #pragma unroll
        for (int rr = 0; rr < 4; ++rr) {
            float v = z[ms][rr];
            v += __shfl_xor(v, 1);
            v += __shfl_xor(v, 2);
            v += __shfl_xor(v, 4);
            v += __shfl_xor(v, 8);
            if (c == 0) zred[wv][ms*16 + g*4 + rr] = v;
        }
    }
    __syncthreads();
    if (tid < 64) {
        float s = zred[0][tid] + zred[1][tid] + zred[2][tid] + zred[3][tid];
        zinv[(size_t)bh*NN + m0 + tid] = 1.0f / s;
    }
}

// ---------------- vzb[bh][dp][m] = bf16(v[dp][m] * zinv[m]), pad rows 0 --
__global__ __launch_bounds__(256)
void vz_kernel(const unsigned short* __restrict__ vb,
               const float* __restrict__ zinv,
               unsigned short* __restrict__ vzb)
{
    size_t idx = (size_t)blockIdx.x*256 + threadIdx.x;   // over NBH*HDP*NN
    int m  = (int)(idx % NN);
    int t  = (int)(idx / NN);
    int dp = t % HDP;
    int bh = t / HDP;
    float val = 0.f;
    if (dp < HD)
        val = bf2f(vb[((size_t)bh*HD + dp)*NN + m]) * zinv[(size_t)bh*NN + m];
    vzb[idx] = f2bf(val);
}

// ---------------- Pass 2: out = Vz * exp2(Q^T K) ------------------------
// S160 structure (R4/R9 passing). R10 deltas: __launch_bounds__(256,4)
// (128 VGPR) + 1-deep Q/Vz-frag prefetch pipeline in the m-loop.
// 1920 blocks: block owns 64 n-cols, kb[4] in regs; 4 waves each accumulate
// a private m-quarter; LDS reduce; wave 0 writes.
__global__ __launch_bounds__(256, 4)
void attn_out_kernel(const unsigned short* __restrict__ qt,
                     const unsigned short* __restrict__ kt,
                     const unsigned short* __restrict__ vzb,
                     float* __restrict__ y)
{
    __shared__ float red[3][32][64];   // 24 KB: waves 1..3 partials
    const int blk  = blockIdx.x;
    const int bh   = blk / (NN/64);
    const int n0   = (blk % (NN/64)) * 64;
    const int tid  = threadIdx.x;
    const int wv   = tid >> 6;
    const int lane = tid & 63;
    const int g = lane >> 4, c = lane & 15;
    const int b = bh >> 3, nh = bh & 7;

    const f32x4 zero4 = {0.f, 0.f, 0.f, 0.f};
    const unsigned short* qb  = qt  + (size_t)bh*NN*HDP;
    const unsigned short* kbp = kt  + (size_t)bh*NN*HDP;
    const unsigned short* vp  = vzb + (size_t)bh*HDP*NN;

    s16x8 kb[4];
    #pragma unroll
    for (int ns = 0; ns < 4; ++ns)
        kb[ns] = *(const s16x8*)(kbp + ((size_t)(n0 + ns*16 + c))*HDP + g*8);

    f32x4 acc[2][4];
    #pragma unroll
    for (int ds = 0; ds < 2; ++ds)
        #pragma unroll
        for (int ns = 0; ns < 4; ++ns) acc[ds][ns] = zero4;

    const int mbeg = wv * (NN/4);
    const int mend = mbeg + NN/4;

    // prologue: load step-0 fragments
    s16x8 qa0 = *(const s16x8*)(qb + ((size_t)(mbeg +      c))*HDP + g*8);
    s16x8 qa1 = *(const s16x8*)(qb + ((size_t)(mbeg + 16 + c))*HDP + g*8);
    s16x4 va00 = *(const s16x4*)(vp + ((size_t)(      c))*NN + mbeg +      g*4);
    s16x4 va01 = *(const s16x4*)(vp + ((size_t)(      c))*NN + mbeg + 16 + g*4);
    s16x4 va10 = *(const s16x4*)(vp + ((size_t)(16 + c))*NN + mbeg +      g*4);
    s16x4 va11 = *(const s16x4*)(vp + ((size_t)(16 + c))*NN + mbeg + 16 + g*4);

    for (int m0 = mbeg; m0 < mend - 32; m0 += 32) {
        // issue next step's loads before computing current step
        const int m1 = m0 + 32;
        s16x8 nqa0 = *(const s16x8*)(qb + ((size_t)(m1 +      c))*HDP + g*8);
        s16x8 nqa1 = *(const s16x8*)(qb + ((size_t)(m1 + 16 + c))*HDP + g*8);
        s16x4 nva00 = *(const s16x4*)(vp + ((size_t)(      c))*NN + m1 +      g*4);
        s16x4 nva01 = *(const s16x4*)(vp + ((size_t)(      c))*NN + m1 + 16 + g*4);
        s16x4 nva10 = *(const s16x4*)(vp + ((size_t)(16 + c))*NN + m1 +      g*4);
        s16x4 nva11 = *(const s16x4*)(vp + ((size_t)(16 + c))*NN + m1 + 16 + g*4);

        #pragma unroll
        for (int ns = 0; ns < 4; ++ns) {
            f32x4 e0 = mfma32(qa0, kb[ns], zero4);
            f32x4 e1 = mfma32(qa1, kb[ns], zero4);
            s16x4 p0 = exp4_pack(e0);
            s16x4 p1 = exp4_pack(e1);
            acc[0][ns] = mfma16(va00, p0, acc[0][ns]);
            acc[0][ns] = mfma16(va01, p1, acc[0][ns]);
            acc[1][ns] = mfma16(va10, p0, acc[1][ns]);
            acc[1][ns] = mfma16(va11, p1, acc[1][ns]);
        }
        qa0 = nqa0; qa1 = nqa1;
        va00 = nva00; va01 = nva01; va10 = nva10; va11 = nva11;
    }
    // epilogue: last step
    #pragma unroll
    for (int ns = 0; ns < 4; ++ns) {
        f32x4 e0 = mfma32(qa0, kb[ns], zero4);
        f32x4 e1 = mfma32(qa1, kb[ns], zero4);
        s16x4 p0 = exp4_pack(e0);
        s16x4 p1 = exp4_pack(e1);
        acc[0][ns] = mfma16(va00, p0, acc[0][ns]);
        acc[0][ns] = mfma16(va01, p1, acc[0][ns]);
        acc[1][ns] = mfma16(va10, p0, acc[1][ns]);
        acc[1][ns] = mfma16(va11, p1, acc[1][ns]);
    }

    float* af = (float*)acc;   // 32 contiguous f32
    if (wv > 0) {
        #pragma unroll
        for (int j = 0; j < 32; ++j) red[wv-1][j][lane] = af[j];
    }
    __syncthreads();
    if (wv == 0) {
        #pragma unroll
        for (int j = 0; j < 32; ++j)
            af[j] += red[0][j][lane] + red[1][j][lane] + red[2][j][lane];
        float* yb = y + (size_t)b * CC * HH * WW;
        #pragma unroll
        for (int ds = 0; ds < 2; ++ds) {
            #pragma unroll
            for (int ns = 0; ns < 4; ++ns) {
                #pragma unroll
                for (int rr = 0; rr < 4; ++rr) {
                    int dd = ds*16 + g*4 + rr;
                    if (dd < HD)
                        yb[((size_t)(dd*NH_ + nh))*NN + n0 + ns*16 + c] = acc[ds][ns][rr];
                }
            }
        }
    }
}

extern "C" void kernel_launch(void* const* d_in, const int* in_sizes, int n_in,
                              void* d_out, int out_size, void* d_ws, size_t ws_size,
                              hipStream_t stream)
{
    const float* x  = (const float*)d_in[0];
    const float* Wq = (const float*)d_in[1];
    const float* bq = (const float*)d_in[2];
    const float* Wk = (const float*)d_in[3];
    const float* bk = (const float*)d_in[4];
    const float* Wv = (const float*)d_in[5];
    const float* bv = (const float*)d_in[6];
    float* y = (float*)d_out;

    const size_t QT_E = (size_t)NBH * NN * HDP;      // 3,932,160 bf16
    unsigned short* qt  = (unsigned short*)d_ws;
    unsigned short* kt  = qt + QT_E;
    unsigned short* vb  = kt + QT_E;
    unsigned short* vzb = vb + (size_t)NBH * HD * NN;
    float*          zinv = (float*)(vzb + QT_E);
    unsigned short* wqb = (unsigned short*)(zinv + (size_t)NBH*NN);
    unsigned short* wkb = wqb + WW*WW;
    unsigned short* wvb = wkb + WW*WW;               // total ~29.2 MB

    hipMemsetAsync(qt, 0, 2 * QT_E * sizeof(unsigned short), stream);

    wprep_kernel<<<dim3((WW*WW + 255)/256), dim3(256), 0, stream>>>(
        Wq, Wk, Wv, wqb, wkb, wvb);
    proj_mfma_kernel<<<dim3(BB*ROWS/64), dim3(256), 0, stream>>>(
        x, wqb, wkb, wvb, bq, bk, bv, qt, kt, vb);
    zinv_kernel<<<dim3(NBH*(NN/64)), dim3(256), 0, stream>>>(qt, kt, zinv);
    vz_kernel<<<dim3((NBH*HDP*NN)/256), dim3(256), 0, stream>>>(vb, zinv, vzb);
    attn_out_kernel<<<dim3(NBH*(NN/64)), dim3(256), 0, stream>>>(qt, kt, vzb, y);
}